// Round 8
// baseline (172.859 us; speedup 1.0000x reference)
//
#include <hip/hip_runtime.h>
#include <hip/hip_bf16.h>
#include <float.h>
#include <stdint.h>

#define N 8192
#define D 512
#define DZ 64
#define KNN 10
#define KSEL 16
#define REGC 1e-6f
#define KEYBIAS 4096.0f

#define BI 128
#define BJ 128
#define BK 32
#define NCHUNK 16
#define JCHUNK (N / NCHUNK)  // 512
#define NJT (JCHUNK / BJ)    // 4
#define NKT (D / BK)         // 16
#define NT (NJT * NKT)       // 64

typedef __attribute__((ext_vector_type(8))) short short8v;
typedef __attribute__((ext_vector_type(4))) float f32x4;
typedef __attribute__((ext_vector_type(4))) int int4v;
typedef __attribute__((ext_vector_type(4))) uint uint4v;

#define WAITV0 asm volatile("s_waitcnt vmcnt(0)" ::: "memory")
#define WAITL0 asm volatile("s_waitcnt lgkmcnt(0)" ::: "memory")
#define BAR __builtin_amdgcn_s_barrier()

__device__ __forceinline__ void gld16(const ushort* g, ushort* l) {
  __builtin_amdgcn_global_load_lds(
      (const __attribute__((address_space(1))) uint32_t*)g,
      (__attribute__((address_space(3))) uint32_t*)l, 16, 0, 0);
}

// branchless sorted-insert into ascending 4-list (7 min/max)
#define INS4(L, xv)                                                  \
  do {                                                               \
    uint _x = (xv);                                                  \
    uint _l0 = _x < L[0] ? _x : L[0];                                \
    uint _h0 = _x < L[0] ? L[0] : _x;                                \
    L[0] = _l0;                                                      \
    uint _l1 = _h0 < L[1] ? _h0 : L[1];                              \
    uint _h1 = _h0 < L[1] ? L[1] : _h0;                              \
    L[1] = _l1;                                                      \
    uint _l2 = _h1 < L[2] ? _h1 : L[2];                              \
    uint _h2 = _h1 < L[2] ? L[2] : _h1;                              \
    L[2] = _l2;                                                      \
    L[3] = _h2 < L[3] ? _h2 : L[3];                                  \
  } while (0)

// ---------------- kernel 0: sqb = |x|^2 + bias, bf16 copy ----------------
__global__ __launch_bounds__(64) void prep_kernel(const float* __restrict__ X,
                                                  float* __restrict__ sqb,
                                                  ushort* __restrict__ Xb) {
  const int i = blockIdx.x;
  const int lane = threadIdx.x;
  const float4 v0 = *(const float4*)&X[(size_t)i * D + lane * 8];
  const float4 v1 = *(const float4*)&X[(size_t)i * D + lane * 8 + 4];
  float vv[8] = {v0.x, v0.y, v0.z, v0.w, v1.x, v1.y, v1.z, v1.w};
  ushort h[8];
  float s = 0.f;
#pragma unroll
  for (int j = 0; j < 8; ++j) {
    s = fmaf(vv[j], vv[j], s);
    __hip_bfloat16 b = __float2bfloat16(vv[j]);
    h[j] = *(ushort*)&b;
  }
  *(int4v*)&Xb[(size_t)i * D + lane * 8] = *(int4v*)h;
#pragma unroll
  for (int off = 32; off; off >>= 1) s += __shfl_xor(s, off);
  if (lane == 0) sqb[i] = s + KEYBIAS;
}

// ---------------- kernel 1: MFMA GEMM + wave-private barrier-free selection ----------------
// Each wave (wr,wc) owns a 64x64 quadrant; keys redistribution goes through a
// private 2KB LDS slice (8 phases of 64x8 u32, XOR-swizzled) with intra-wave
// lgkmcnt ordering only -- ZERO selection barriers. Waves skew; setprio(1)
// keeps the MFMA pipe fed while other waves run selection VALU.
__global__ __launch_bounds__(256, 4) void knn_kernel(const ushort* __restrict__ Xb,
                                                     const float* __restrict__ sqb,
                                                     uint* __restrict__ cand) {
  __shared__ ushort As[2][BI][BK];  // 16 KB
  __shared__ ushort Bs[2][BJ][BK];  // 16 KB
  __shared__ uint keys[4][512];     // 8 KB: per-wave private 64x8 slice

  const int i0 = blockIdx.x * BI;
  const int chunk = blockIdx.y;
  const int jbase = chunk * JCHUNK;
  const int tid = threadIdx.x;
  const int lane = tid & 63;
  const int wave = tid >> 6;
  const int wr = wave >> 1, wc = wave & 1;
  const int q = lane >> 4, cr = lane & 15;

  // staging: thread -> 16B; LDS dest linear, source col pre-swizzled
  const int srow = tid >> 2, sg = tid & 3;
  const int scsw = (sg ^ ((srow >> 1) & 3)) * 8;
  const size_t aoff0 = (size_t)(i0 + srow) * D + scsw;
  const size_t aoff1 = (size_t)(i0 + 64 + srow) * D + scsw;
  const size_t boff0 = (size_t)(jbase + srow) * D + scsw;

  // fragment read col (swizzle reduces to lane constant)
  const int fcol = (q ^ ((cr >> 1) & 3)) * 8;

  uint* const kw = &keys[wave][0];

  uint LA[4], LB[4];
#pragma unroll
  for (int k = 0; k < 4; ++k) {
    LA[k] = 0xFFFFFFFFu;
    LB[k] = 0xFFFFFFFFu;
  }

  auto STAGE = [&](int tt) {
    const int jt_ = tt >> 4;
    const int bf = tt & 1;
    const int ko = (tt & 15) * BK;
    gld16(Xb + aoff0 + ko, &As[bf][srow][sg * 8]);
    gld16(Xb + aoff1 + ko, &As[bf][64 + srow][sg * 8]);
    const size_t bo = boff0 + (size_t)jt_ * (BJ * D) + ko;
    gld16(Xb + bo, &Bs[bf][srow][sg * 8]);
    gld16(Xb + bo + (size_t)64 * D, &Bs[bf][64 + srow][sg * 8]);
  };

  f32x4 acc[4][4];
#pragma unroll
  for (int m = 0; m < 4; ++m)
#pragma unroll
    for (int n = 0; n < 4; ++n) acc[m][n] = (f32x4){0.f, 0.f, 0.f, 0.f};

  STAGE(0);

#pragma unroll 1
  for (int t = 0; t < NT; ++t) {
    const int buf = t & 1;
    WAITV0;  // my 4 loads for this K-step landed
    BAR;     // everyone's landed; prior frag reads done
    STAGE((t + 1) & (NT - 1));  // next step flies under the MFMAs

    const ushort(*Ab)[BK] = As[buf];
    const ushort(*Bb)[BK] = Bs[buf];
    short8v a[4], b[4];
#pragma unroll
    for (int m = 0; m < 4; ++m)
      a[m] = *(const short8v*)&Ab[wr * 64 + m * 16 + cr][fcol];
#pragma unroll
    for (int n = 0; n < 4; ++n)
      b[n] = *(const short8v*)&Bb[wc * 64 + n * 16 + cr][fcol];
    __builtin_amdgcn_s_setprio(1);
#pragma unroll
    for (int m = 0; m < 4; ++m)
#pragma unroll
      for (int n = 0; n < 4; ++n)
        acc[m][n] = __builtin_amdgcn_mfma_f32_16x16x32_bf16(a[m], b[n], acc[m][n], 0, 0, 0);
    __builtin_amdgcn_s_setprio(0);

    if ((t & 15) == 15) {  // end of jt: wave-private selection, 8 phases x 8 cols
      const int jt = t >> 4;
#pragma unroll
      for (int p = 0; p < 8; ++p) {
        const int n = p >> 1, hf = p & 1;
        if ((cr >> 3) == hf) {  // 32 writer lanes; wave64 lockstep, no barrier
          const float sqjb = sqb[jbase + jt * BJ + wc * 64 + n * 16 + cr];
          const uint idxn = (uint)(jt * 128 + wc * 64 + n * 16 + cr);
#pragma unroll
          for (int m = 0; m < 4; ++m)
#pragma unroll
            for (int s = 0; s < 4; ++s) {
              const int row4 = q * 4 + s;
              const float f = fmaf(-2.f, acc[m][n][s], sqjb);  // > 0 by bias
              kw[(m * 16 + row4) * 8 + ((cr & 7) ^ (row4 & 7))] =
                  (__float_as_uint(f) & 0xFFFFFC00u) | idxn;
            }
        }
        WAITL0;  // intra-wave write->read ordering (memory clobber orders DS ops)
        // lane = row; b128 pairs, XOR-permuted within quad (order-free for INS4)
        const uint4v v0 = *(const uint4v*)(kw + lane * 8 + (lane & 4));
        const uint4v v1 = *(const uint4v*)(kw + lane * 8 + ((lane & 4) ^ 4));
        if (jt < 2) {
          INS4(LA, v0[0]); INS4(LA, v0[1]); INS4(LA, v0[2]); INS4(LA, v0[3]);
          INS4(LA, v1[0]); INS4(LA, v1[1]); INS4(LA, v1[2]); INS4(LA, v1[3]);
        } else {
          INS4(LB, v0[0]); INS4(LB, v0[1]); INS4(LB, v0[2]); INS4(LB, v0[3]);
          INS4(LB, v1[0]); INS4(LB, v1[1]); INS4(LB, v1[2]); INS4(LB, v1[3]);
        }
        WAITL0;  // reads retired before next phase overwrites the slice
      }
#pragma unroll
      for (int m = 0; m < 4; ++m)
#pragma unroll
        for (int n = 0; n < 4; ++n) acc[m][n] = (f32x4){0.f, 0.f, 0.f, 0.f};
    }
  }

  // lane = wave-local row; wc picks the 8-slot half of the 16-cand chunk list
  const int gi = i0 + wr * 64 + lane;
  uint* dst = &cand[((size_t)gi * NCHUNK + chunk) * KSEL + wc * 8];
#pragma unroll
  for (int k = 0; k < 4; ++k) {
    dst[k] = LA[k];
    dst[4 + k] = LB[k];
  }
}

// ---------------- kernel 2: 4 rows/block (4 indep waves), LDS-free ----------------
__global__ __launch_bounds__(256) void lle_loss_kernel(
    const float* __restrict__ X, const float* __restrict__ Z,
    const float* __restrict__ sqb, const uint* __restrict__ cand,
    float* __restrict__ rowsse) {
  const int lane = threadIdx.x & 63;
  const int i = blockIdx.x * 4 + (threadIdx.x >> 6);

  // 256 entries (16 chunks x 16) -> unique u64 (approx key || gidx13)
  const uint4v pk4 = *(const uint4v*)&cand[(size_t)i * 256 + lane * 4];
  const int chk = lane >> 2;  // (lane*4+kk)>>4 for kk=0..3
  unsigned long long cvm[4];
#pragma unroll
  for (int kk = 0; kk < 4; ++kk) {
    const int g = chk * JCHUNK + (int)(pk4[kk] & 0x3FFu);
    const unsigned long long kv =
        ((unsigned long long)(pk4[kk] >> 10) << 13) | (unsigned long long)g;
    cvm[kk] = (g == i) ? ~0ull : kv;  // self-exclusion
  }

  // approx top-16 via 16x butterfly argmin; every lane keeps all results
  int cidx[KSEL];
#pragma unroll
  for (int k = 0; k < KSEL; ++k) {
    const unsigned long long m01 = cvm[0] < cvm[1] ? cvm[0] : cvm[1];
    const unsigned long long m23 = cvm[2] < cvm[3] ? cvm[2] : cvm[3];
    unsigned long long mn = m01 < m23 ? m01 : m23;
#pragma unroll
    for (int off = 32; off; off >>= 1) {
      const unsigned long long o = __shfl_xor(mn, off);
      mn = o < mn ? o : mn;
    }
    cidx[k] = (int)(mn & 0x1FFFull);
#pragma unroll
    for (int kk = 0; kk < 4; ++kk)
      cvm[kk] = (cvm[kk] == mn) ? ~0ull : cvm[kk];  // values unique
  }

  float xi[8];
  {
    const float4 v0 = *(const float4*)&X[(size_t)i * D + lane * 8];
    const float4 v1 = *(const float4*)&X[(size_t)i * D + lane * 8 + 4];
    xi[0] = v0.x; xi[1] = v0.y; xi[2] = v0.z; xi[3] = v0.w;
    xi[4] = v1.x; xi[5] = v1.y; xi[6] = v1.z; xi[7] = v1.w;
  }

  // exact fp32 rescore; key = biased-positive fp32 bits (exact order) || gidx
  unsigned long long cv[KSEL];
#pragma unroll
  for (int k = 0; k < KSEL; ++k) {
    const int j = cidx[k];
    const float4 u0 = *(const float4*)&X[(size_t)j * D + lane * 8];
    const float4 u1 = *(const float4*)&X[(size_t)j * D + lane * 8 + 4];
    float p = 0.f;
    p = fmaf(xi[0], u0.x, p); p = fmaf(xi[1], u0.y, p);
    p = fmaf(xi[2], u0.z, p); p = fmaf(xi[3], u0.w, p);
    p = fmaf(xi[4], u1.x, p); p = fmaf(xi[5], u1.y, p);
    p = fmaf(xi[6], u1.z, p); p = fmaf(xi[7], u1.w, p);
#pragma unroll
    for (int off = 32; off; off >>= 1) p += __shfl_xor(p, off);
    const float f = fmaf(-2.f, p, sqb[j]);  // > 0, all lanes hold it
    cv[k] = ((unsigned long long)__float_as_uint(f) << 32) | (unsigned long long)(uint)j;
  }

  // exact top-10 of 16 via compare-exchange network (all lanes, registers)
  unsigned long long T[KNN];
#pragma unroll
  for (int k = 0; k < KNN; ++k) T[k] = ~0ull;
#pragma unroll
  for (int c = 0; c < KSEL; ++c) {
    unsigned long long x = cv[c];
#pragma unroll
    for (int qq = 0; qq < KNN; ++qq) {
      const unsigned long long lo = x < T[qq] ? x : T[qq];
      const unsigned long long hi = x < T[qq] ? T[qq] : x;
      T[qq] = lo;
      x = hi;
    }
  }
  int nbrj[KNN];
#pragma unroll
  for (int k = 0; k < KNN; ++k) nbrj[k] = (int)(T[k] & 0x1FFFull);

  // diffs in registers (lane owns 8 contiguous dims)
  float df[KNN][8];
#pragma unroll
  for (int k = 0; k < KNN; ++k) {
    const int j = nbrj[k];
    const float4 u0 = *(const float4*)&X[(size_t)j * D + lane * 8];
    const float4 u1 = *(const float4*)&X[(size_t)j * D + lane * 8 + 4];
    df[k][0] = u0.x - xi[0]; df[k][1] = u0.y - xi[1];
    df[k][2] = u0.z - xi[2]; df[k][3] = u0.w - xi[3];
    df[k][4] = u1.x - xi[4]; df[k][5] = u1.y - xi[5];
    df[k][6] = u1.z - xi[6]; df[k][7] = u1.w - xi[7];
  }

  // Gram lower triangle via butterfly reductions -> every lane has C
  float C[KNN][KNN];
#pragma unroll
  for (int k = 0; k < KNN; ++k) {
#pragma unroll
    for (int l = 0; l <= k; ++l) {
      float p = 0.f;
#pragma unroll
      for (int c = 0; c < 8; ++c) p = fmaf(df[k][c], df[l][c], p);
#pragma unroll
      for (int off = 32; off; off >>= 1) p += __shfl_xor(p, off);
      C[k][l] = p;
    }
  }

  // all-lane static-register Cholesky + solve (zero LDS, zero divergence)
  float dinv[KNN];
#pragma unroll
  for (int j = 0; j < KNN; ++j) {
    float s = C[j][j] + REGC;
#pragma unroll
    for (int t = 0; t < KNN; ++t)
      if (t < j) s -= C[j][t] * C[j][t];
    const float dj = sqrtf(s);
    const float inv = 1.f / dj;
    dinv[j] = inv;
#pragma unroll
    for (int r2 = 0; r2 < KNN; ++r2) {
      if (r2 > j) {
        float s2 = C[r2][j];
#pragma unroll
        for (int t = 0; t < KNN; ++t)
          if (t < j) s2 -= C[r2][t] * C[j][t];
        C[r2][j] = s2 * inv;
      }
    }
  }
  float y[KNN], w[KNN];
#pragma unroll
  for (int r2 = 0; r2 < KNN; ++r2) {  // L y = 1
    float s = 1.f;
#pragma unroll
    for (int t = 0; t < KNN; ++t)
      if (t < r2) s -= C[r2][t] * y[t];
    y[r2] = s * dinv[r2];
  }
#pragma unroll
  for (int r2 = KNN - 1; r2 >= 0; --r2) {  // L^T w = y
    float s2 = y[r2];
#pragma unroll
    for (int t = 0; t < KNN; ++t)
      if (t > r2) s2 -= C[t][r2] * w[t];
    w[r2] = s2 * dinv[r2];
  }
  float ws = 0.f;
#pragma unroll
  for (int k = 0; k < KNN; ++k) ws += w[k];
  const float winv = 1.f / ws;

  // reconstruction (lane == output dim, DZ == 64)
  float zr = 0.f;
#pragma unroll
  for (int k = 0; k < KNN; ++k)
    zr = fmaf(w[k] * winv, Z[(size_t)nbrj[k] * DZ + lane], zr);
  const float e = zr - Z[(size_t)i * DZ + lane];
  float se = e * e;
#pragma unroll
  for (int off = 32; off; off >>= 1) se += __shfl_xor(se, off);
  if (lane == 0) rowsse[i] = se;  // plain store: no atomic contention
}

// ---------------- kernel 3: single-block final reduction ----------------
__global__ __launch_bounds__(256) void reduce_kernel(const float* __restrict__ rowsse,
                                                     float* __restrict__ out) {
  const int tid = threadIdx.x;
  float s = 0.f;
#pragma unroll
  for (int c = 0; c < N / 256; ++c) s += rowsse[c * 256 + tid];
#pragma unroll
  for (int off = 32; off; off >>= 1) s += __shfl_xor(s, off);
  __shared__ float part[4];
  if ((tid & 63) == 0) part[tid >> 6] = s;
  __syncthreads();
  if (tid == 0)
    out[0] = (part[0] + part[1] + part[2] + part[3]) * (1.f / ((float)N * DZ));
}

// ---------------- launch ----------------
extern "C" void kernel_launch(void* const* d_in, const int* in_sizes, int n_in,
                              void* d_out, int out_size, void* d_ws, size_t ws_size,
                              hipStream_t stream) {
  const float* X = (const float*)d_in[0];
  const float* Z = (const float*)d_in[1];
  float* out = (float*)d_out;

  char* ws = (char*)d_ws;
  float* sqb = (float*)ws;                                   // 32 KB
  float* rowsse = (float*)(ws + 32 * 1024);                  // 32 KB
  ushort* Xb = (ushort*)(ws + 64 * 1024);                    // 8 MB
  uint* cand = (uint*)(ws + 64 * 1024 + (size_t)N * D * 2);  // 8 MB

  prep_kernel<<<N, 64, 0, stream>>>(X, sqb, Xb);
  knn_kernel<<<dim3(N / BI, NCHUNK), 256, 0, stream>>>(Xb, sqb, cand);
  lle_loss_kernel<<<N / 4, 256, 0, stream>>>(X, Z, sqb, cand, rowsse);
  reduce_kernel<<<1, 256, 0, stream>>>(rowsse, out);
}

// Round 9
// 167.465 us; speedup vs baseline: 1.0322x; 1.0322x over previous
//
#include <hip/hip_runtime.h>
#include <hip/hip_bf16.h>
#include <float.h>
#include <stdint.h>

#define N 8192
#define D 512
#define DZ 64
#define KNN 10
#define KSEL 16
#define REGC 1e-6f
#define KEYBIAS 4096.0f

#define BI 128
#define BJ 128
#define BK 32
#define NCHUNK 16
#define JCHUNK (N / NCHUNK)  // 512
#define NJT (JCHUNK / BJ)    // 4
#define NKT (D / BK)         // 16
#define NT (NJT * NKT)       // 64

typedef __attribute__((ext_vector_type(8))) short short8v;
typedef __attribute__((ext_vector_type(4))) float f32x4;
typedef __attribute__((ext_vector_type(4))) int int4v;
typedef __attribute__((ext_vector_type(4))) uint uint4v;

#define WAITV0 asm volatile("s_waitcnt vmcnt(0)" ::: "memory")
#define BAR __builtin_amdgcn_s_barrier()

__device__ __forceinline__ void gld16(const ushort* g, ushort* l) {
  __builtin_amdgcn_global_load_lds(
      (const __attribute__((address_space(1))) uint32_t*)g,
      (__attribute__((address_space(3))) uint32_t*)l, 16, 0, 0);
}

// branchless sorted-insert into ascending 4-list (7 min/max)
#define INS4(L, xv)                                                  \
  do {                                                               \
    uint _x = (xv);                                                  \
    uint _l0 = _x < L[0] ? _x : L[0];                                \
    uint _h0 = _x < L[0] ? L[0] : _x;                                \
    L[0] = _l0;                                                      \
    uint _l1 = _h0 < L[1] ? _h0 : L[1];                              \
    uint _h1 = _h0 < L[1] ? L[1] : _h0;                              \
    L[1] = _l1;                                                      \
    uint _l2 = _h1 < L[2] ? _h1 : L[2];                              \
    uint _h2 = _h1 < L[2] ? L[2] : _h1;                              \
    L[2] = _l2;                                                      \
    L[3] = _h2 < L[3] ? _h2 : L[3];                                  \
  } while (0)

// branchless sorted-insert into ascending 8-list (15 min/max)
#define INS8(L, xv)                                                  \
  do {                                                               \
    uint _x = (xv);                                                  \
    uint _a0 = _x < L[0] ? _x : L[0];                                \
    uint _b0 = _x < L[0] ? L[0] : _x;                                \
    L[0] = _a0;                                                      \
    uint _a1 = _b0 < L[1] ? _b0 : L[1];                              \
    uint _b1 = _b0 < L[1] ? L[1] : _b0;                              \
    L[1] = _a1;                                                      \
    uint _a2 = _b1 < L[2] ? _b1 : L[2];                              \
    uint _b2 = _b1 < L[2] ? L[2] : _b1;                              \
    L[2] = _a2;                                                      \
    uint _a3 = _b2 < L[3] ? _b2 : L[3];                              \
    uint _b3 = _b2 < L[3] ? L[3] : _b2;                              \
    L[3] = _a3;                                                      \
    uint _a4 = _b3 < L[4] ? _b3 : L[4];                              \
    uint _b4 = _b3 < L[4] ? L[4] : _b3;                              \
    L[4] = _a4;                                                      \
    uint _a5 = _b4 < L[5] ? _b4 : L[5];                              \
    uint _b5 = _b4 < L[5] ? L[5] : _b4;                              \
    L[5] = _a5;                                                      \
    uint _a6 = _b5 < L[6] ? _b5 : L[6];                              \
    uint _b6 = _b5 < L[6] ? L[6] : _b5;                              \
    L[6] = _a6;                                                      \
    L[7] = _b6 < L[7] ? _b6 : L[7];                                  \
  } while (0)

// ---------------- kernel 0: sqb = |x|^2 + bias, bf16 copy ----------------
__global__ __launch_bounds__(64) void prep_kernel(const float* __restrict__ X,
                                                  float* __restrict__ sqb,
                                                  ushort* __restrict__ Xb) {
  const int i = blockIdx.x;
  const int lane = threadIdx.x;
  const float4 v0 = *(const float4*)&X[(size_t)i * D + lane * 8];
  const float4 v1 = *(const float4*)&X[(size_t)i * D + lane * 8 + 4];
  float vv[8] = {v0.x, v0.y, v0.z, v0.w, v1.x, v1.y, v1.z, v1.w};
  ushort h[8];
  float s = 0.f;
#pragma unroll
  for (int j = 0; j < 8; ++j) {
    s = fmaf(vv[j], vv[j], s);
    __hip_bfloat16 b = __float2bfloat16(vv[j]);
    h[j] = *(ushort*)&b;
  }
  *(int4v*)&Xb[(size_t)i * D + lane * 8] = *(int4v*)h;
#pragma unroll
  for (int off = 32; off; off >>= 1) s += __shfl_xor(s, off);
  if (lane == 0) sqb[i] = s + KEYBIAS;
}

// ---------------- kernel 1: swapped-operand MFMA GEMM, pure-register selection ----------------
// acc[n][m] = mfma(b[n], a[m], ...) -> C-row = j (n*16+q*4+s), C-col = i (m*16+cr).
// Each lane owns 4 rows i and holds its 16 j-candidates/jt IN REGISTERS: selection
// is INS4 straight from acc (no LDS redistribution, no barriers). Final top-8 per
// (row, wc-half) via shfl_xor q-lane merge.
__global__ __launch_bounds__(256, 4) void knn_kernel(const ushort* __restrict__ Xb,
                                                     const float* __restrict__ sqb,
                                                     uint* __restrict__ cand) {
  __shared__ ushort As[2][BI][BK];  // 16 KB
  __shared__ ushort Bs[2][BJ][BK];  // 16 KB  (total 32 KB, no keys buffer)

  const int i0 = blockIdx.x * BI;
  const int chunk = blockIdx.y;
  const int jbase = chunk * JCHUNK;
  const int tid = threadIdx.x;
  const int lane = tid & 63;
  const int wave = tid >> 6;
  const int wr = wave >> 1, wc = wave & 1;
  const int q = lane >> 4, cr = lane & 15;

  // staging: thread -> 16B; LDS dest linear, source col pre-swizzled
  const int srow = tid >> 2, sg = tid & 3;
  const int scsw = (sg ^ ((srow >> 1) & 3)) * 8;
  const size_t aoff0 = (size_t)(i0 + srow) * D + scsw;
  const size_t aoff1 = (size_t)(i0 + 64 + srow) * D + scsw;
  const size_t boff0 = (size_t)(jbase + srow) * D + scsw;

  // fragment read col (swizzle reduces to lane constant)
  const int fcol = (q ^ ((cr >> 1) & 3)) * 8;

  uint Lst[4][4];  // per-lane top-4 list per output row m
#pragma unroll
  for (int m = 0; m < 4; ++m)
#pragma unroll
    for (int k = 0; k < 4; ++k) Lst[m][k] = 0xFFFFFFFFu;

  auto STAGE = [&](int tt) {
    const int jt_ = tt >> 4;
    const int bf = tt & 1;
    const int ko = (tt & 15) * BK;
    gld16(Xb + aoff0 + ko, &As[bf][srow][sg * 8]);
    gld16(Xb + aoff1 + ko, &As[bf][64 + srow][sg * 8]);
    const size_t bo = boff0 + (size_t)jt_ * (BJ * D) + ko;
    gld16(Xb + bo, &Bs[bf][srow][sg * 8]);
    gld16(Xb + bo + (size_t)64 * D, &Bs[bf][64 + srow][sg * 8]);
  };

  f32x4 acc[4][4];  // [n][m]: n = j-group, m = i-group
#pragma unroll
  for (int n = 0; n < 4; ++n)
#pragma unroll
    for (int m = 0; m < 4; ++m) acc[n][m] = (f32x4){0.f, 0.f, 0.f, 0.f};

  STAGE(0);

#pragma unroll 1
  for (int t = 0; t < NT; ++t) {
    const int buf = t & 1;
    WAITV0;  // my 4 loads for this K-step landed
    BAR;     // everyone's landed; prior frag reads done
    STAGE((t + 1) & (NT - 1));  // next step flies under the MFMAs

    const ushort(*Ab)[BK] = As[buf];
    const ushort(*Bb)[BK] = Bs[buf];
    short8v a[4], b[4];
#pragma unroll
    for (int m = 0; m < 4; ++m)
      a[m] = *(const short8v*)&Ab[wr * 64 + m * 16 + cr][fcol];
#pragma unroll
    for (int n = 0; n < 4; ++n)
      b[n] = *(const short8v*)&Bb[wc * 64 + n * 16 + cr][fcol];
    __builtin_amdgcn_s_setprio(1);
#pragma unroll
    for (int n = 0; n < 4; ++n)
#pragma unroll
      for (int m = 0; m < 4; ++m)
        acc[n][m] = __builtin_amdgcn_mfma_f32_16x16x32_bf16(b[n], a[m], acc[n][m], 0, 0, 0);
    __builtin_amdgcn_s_setprio(0);

    if ((t & 15) == 15) {  // end of jt: register-only selection
      const int jt = t >> 4;
      const int jloc = jt * BJ + wc * 64 + q * 4;  // + n*16 + s
#pragma unroll
      for (int n = 0; n < 4; ++n) {
        const float4 s4 = *(const float4*)&sqb[jbase + jloc + n * 16];
        const uint ib = (uint)(jloc + n * 16);
#pragma unroll
        for (int m = 0; m < 4; ++m) {
          const float f0 = fmaf(-2.f, acc[n][m][0], s4.x);
          const float f1 = fmaf(-2.f, acc[n][m][1], s4.y);
          const float f2 = fmaf(-2.f, acc[n][m][2], s4.z);
          const float f3 = fmaf(-2.f, acc[n][m][3], s4.w);
          INS4(Lst[m], (__float_as_uint(f0) & 0xFFFFFC00u) | ib);
          INS4(Lst[m], (__float_as_uint(f1) & 0xFFFFFC00u) | (ib + 1));
          INS4(Lst[m], (__float_as_uint(f2) & 0xFFFFFC00u) | (ib + 2));
          INS4(Lst[m], (__float_as_uint(f3) & 0xFFFFFC00u) | (ib + 3));
        }
      }
#pragma unroll
      for (int n = 0; n < 4; ++n)
#pragma unroll
        for (int m = 0; m < 4; ++m) acc[n][m] = (f32x4){0.f, 0.f, 0.f, 0.f};
    }
  }

  // merge q-lanes (xor16 then xor32) -> top-8 of the wave's 256-stream per row
#pragma unroll
  for (int m = 0; m < 4; ++m) {
    uint L8[8];
#pragma unroll
    for (int k = 0; k < 4; ++k) {
      L8[k] = Lst[m][k];
      L8[4 + k] = 0xFFFFFFFFu;
    }
#pragma unroll
    for (int k = 0; k < 4; ++k) {
      const uint x = __shfl_xor(Lst[m][k], 16);
      INS8(L8, x);
    }
    uint tf[8];
#pragma unroll
    for (int k = 0; k < 8; ++k) tf[k] = __shfl_xor(L8[k], 32);
#pragma unroll
    for (int k = 0; k < 8; ++k) INS8(L8, tf[k]);
    if (q == 0) {
      const int gi = i0 + wr * 64 + m * 16 + cr;
      uint* dst = &cand[((size_t)gi * NCHUNK + chunk) * KSEL + wc * 8];
      *(uint4v*)dst = (uint4v){L8[0], L8[1], L8[2], L8[3]};
      *(uint4v*)(dst + 4) = (uint4v){L8[4], L8[5], L8[6], L8[7]};
    }
  }
}

// ---------------- kernel 2: 4 rows/block (4 indep waves), LDS-free ----------------
__global__ __launch_bounds__(256) void lle_loss_kernel(
    const float* __restrict__ X, const float* __restrict__ Z,
    const float* __restrict__ sqb, const uint* __restrict__ cand,
    float* __restrict__ rowsse) {
  const int lane = threadIdx.x & 63;
  const int i = blockIdx.x * 4 + (threadIdx.x >> 6);

  // 256 entries (16 chunks x 16) -> unique u64 (approx key || gidx13)
  const uint4v pk4 = *(const uint4v*)&cand[(size_t)i * 256 + lane * 4];
  const int chk = lane >> 2;  // (lane*4+kk)>>4 for kk=0..3
  unsigned long long cvm[4];
#pragma unroll
  for (int kk = 0; kk < 4; ++kk) {
    const int g = chk * JCHUNK + (int)(pk4[kk] & 0x3FFu);
    const unsigned long long kv =
        ((unsigned long long)(pk4[kk] >> 10) << 13) | (unsigned long long)g;
    cvm[kk] = (g == i) ? ~0ull : kv;  // self-exclusion
  }

  // approx top-16 via 16x butterfly argmin; every lane keeps all results
  int cidx[KSEL];
#pragma unroll
  for (int k = 0; k < KSEL; ++k) {
    const unsigned long long m01 = cvm[0] < cvm[1] ? cvm[0] : cvm[1];
    const unsigned long long m23 = cvm[2] < cvm[3] ? cvm[2] : cvm[3];
    unsigned long long mn = m01 < m23 ? m01 : m23;
#pragma unroll
    for (int off = 32; off; off >>= 1) {
      const unsigned long long o = __shfl_xor(mn, off);
      mn = o < mn ? o : mn;
    }
    cidx[k] = (int)(mn & 0x1FFFull);
#pragma unroll
    for (int kk = 0; kk < 4; ++kk)
      cvm[kk] = (cvm[kk] == mn) ? ~0ull : cvm[kk];  // values unique
  }

  float xi[8];
  {
    const float4 v0 = *(const float4*)&X[(size_t)i * D + lane * 8];
    const float4 v1 = *(const float4*)&X[(size_t)i * D + lane * 8 + 4];
    xi[0] = v0.x; xi[1] = v0.y; xi[2] = v0.z; xi[3] = v0.w;
    xi[4] = v1.x; xi[5] = v1.y; xi[6] = v1.z; xi[7] = v1.w;
  }

  // exact fp32 rescore; key = biased-positive fp32 bits (exact order) || gidx
  unsigned long long cv[KSEL];
#pragma unroll
  for (int k = 0; k < KSEL; ++k) {
    const int j = cidx[k];
    const float4 u0 = *(const float4*)&X[(size_t)j * D + lane * 8];
    const float4 u1 = *(const float4*)&X[(size_t)j * D + lane * 8 + 4];
    float p = 0.f;
    p = fmaf(xi[0], u0.x, p); p = fmaf(xi[1], u0.y, p);
    p = fmaf(xi[2], u0.z, p); p = fmaf(xi[3], u0.w, p);
    p = fmaf(xi[4], u1.x, p); p = fmaf(xi[5], u1.y, p);
    p = fmaf(xi[6], u1.z, p); p = fmaf(xi[7], u1.w, p);
#pragma unroll
    for (int off = 32; off; off >>= 1) p += __shfl_xor(p, off);
    const float f = fmaf(-2.f, p, sqb[j]);  // > 0, all lanes hold it
    cv[k] = ((unsigned long long)__float_as_uint(f) << 32) | (unsigned long long)(uint)j;
  }

  // exact top-10 of 16 via compare-exchange network (all lanes, registers)
  unsigned long long T[KNN];
#pragma unroll
  for (int k = 0; k < KNN; ++k) T[k] = ~0ull;
#pragma unroll
  for (int c = 0; c < KSEL; ++c) {
    unsigned long long x = cv[c];
#pragma unroll
    for (int qq = 0; qq < KNN; ++qq) {
      const unsigned long long lo = x < T[qq] ? x : T[qq];
      const unsigned long long hi = x < T[qq] ? T[qq] : x;
      T[qq] = lo;
      x = hi;
    }
  }
  int nbrj[KNN];
#pragma unroll
  for (int k = 0; k < KNN; ++k) nbrj[k] = (int)(T[k] & 0x1FFFull);

  // diffs in registers (lane owns 8 contiguous dims)
  float df[KNN][8];
#pragma unroll
  for (int k = 0; k < KNN; ++k) {
    const int j = nbrj[k];
    const float4 u0 = *(const float4*)&X[(size_t)j * D + lane * 8];
    const float4 u1 = *(const float4*)&X[(size_t)j * D + lane * 8 + 4];
    df[k][0] = u0.x - xi[0]; df[k][1] = u0.y - xi[1];
    df[k][2] = u0.z - xi[2]; df[k][3] = u0.w - xi[3];
    df[k][4] = u1.x - xi[4]; df[k][5] = u1.y - xi[5];
    df[k][6] = u1.z - xi[6]; df[k][7] = u1.w - xi[7];
  }

  // Gram lower triangle via butterfly reductions -> every lane has C
  float C[KNN][KNN];
#pragma unroll
  for (int k = 0; k < KNN; ++k) {
#pragma unroll
    for (int l = 0; l <= k; ++l) {
      float p = 0.f;
#pragma unroll
      for (int c = 0; c < 8; ++c) p = fmaf(df[k][c], df[l][c], p);
#pragma unroll
      for (int off = 32; off; off >>= 1) p += __shfl_xor(p, off);
      C[k][l] = p;
    }
  }

  // all-lane static-register Cholesky + solve (zero LDS, zero divergence)
  float dinv[KNN];
#pragma unroll
  for (int j = 0; j < KNN; ++j) {
    float s = C[j][j] + REGC;
#pragma unroll
    for (int t = 0; t < KNN; ++t)
      if (t < j) s -= C[j][t] * C[j][t];
    const float dj = sqrtf(s);
    const float inv = 1.f / dj;
    dinv[j] = inv;
#pragma unroll
    for (int r2 = 0; r2 < KNN; ++r2) {
      if (r2 > j) {
        float s2 = C[r2][j];
#pragma unroll
        for (int t = 0; t < KNN; ++t)
          if (t < j) s2 -= C[r2][t] * C[j][t];
        C[r2][j] = s2 * inv;
      }
    }
  }
  float y[KNN], w[KNN];
#pragma unroll
  for (int r2 = 0; r2 < KNN; ++r2) {  // L y = 1
    float s = 1.f;
#pragma unroll
    for (int t = 0; t < KNN; ++t)
      if (t < r2) s -= C[r2][t] * y[t];
    y[r2] = s * dinv[r2];
  }
#pragma unroll
  for (int r2 = KNN - 1; r2 >= 0; --r2) {  // L^T w = y
    float s2 = y[r2];
#pragma unroll
    for (int t = 0; t < KNN; ++t)
      if (t > r2) s2 -= C[t][r2] * w[t];
    w[r2] = s2 * dinv[r2];
  }
  float ws = 0.f;
#pragma unroll
  for (int k = 0; k < KNN; ++k) ws += w[k];
  const float winv = 1.f / ws;

  // reconstruction (lane == output dim, DZ == 64)
  float zr = 0.f;
#pragma unroll
  for (int k = 0; k < KNN; ++k)
    zr = fmaf(w[k] * winv, Z[(size_t)nbrj[k] * DZ + lane], zr);
  const float e = zr - Z[(size_t)i * DZ + lane];
  float se = e * e;
#pragma unroll
  for (int off = 32; off; off >>= 1) se += __shfl_xor(se, off);
  if (lane == 0) rowsse[i] = se;  // plain store: no atomic contention
}

// ---------------- kernel 3: single-block final reduction ----------------
__global__ __launch_bounds__(256) void reduce_kernel(const float* __restrict__ rowsse,
                                                     float* __restrict__ out) {
  const int tid = threadIdx.x;
  float s = 0.f;
#pragma unroll
  for (int c = 0; c < N / 256; ++c) s += rowsse[c * 256 + tid];
#pragma unroll
  for (int off = 32; off; off >>= 1) s += __shfl_xor(s, off);
  __shared__ float part[4];
  if ((tid & 63) == 0) part[tid >> 6] = s;
  __syncthreads();
  if (tid == 0)
    out[0] = (part[0] + part[1] + part[2] + part[3]) * (1.f / ((float)N * DZ));
}

// ---------------- launch ----------------
extern "C" void kernel_launch(void* const* d_in, const int* in_sizes, int n_in,
                              void* d_out, int out_size, void* d_ws, size_t ws_size,
                              hipStream_t stream) {
  const float* X = (const float*)d_in[0];
  const float* Z = (const float*)d_in[1];
  float* out = (float*)d_out;

  char* ws = (char*)d_ws;
  float* sqb = (float*)ws;                                   // 32 KB
  float* rowsse = (float*)(ws + 32 * 1024);                  // 32 KB
  ushort* Xb = (ushort*)(ws + 64 * 1024);                    // 8 MB
  uint* cand = (uint*)(ws + 64 * 1024 + (size_t)N * D * 2);  // 8 MB

  prep_kernel<<<N, 64, 0, stream>>>(X, sqb, Xb);
  knn_kernel<<<dim3(N / BI, NCHUNK), 256, 0, stream>>>(Xb, sqb, cand);
  lle_loss_kernel<<<N / 4, 256, 0, stream>>>(X, Z, sqb, cand, rowsse);
  reduce_kernel<<<1, 256, 0, stream>>>(rowsse, out);
}

// Round 10
// 144.215 us; speedup vs baseline: 1.1986x; 1.1612x over previous
//
#include <hip/hip_runtime.h>
#include <hip/hip_bf16.h>
#include <float.h>
#include <stdint.h>

#define N 8192
#define D 512
#define DZ 64
#define KNN 10
#define KSEL 16
#define REGC 1e-6f
#define KEYBIAS 4096.0f

#define BI 128
#define BJ 128
#define BK 32
#define NCHUNK 16
#define JCHUNK (N / NCHUNK)  // 512
#define NJT (JCHUNK / BJ)    // 4
#define NKT (D / BK)         // 16
#define NT (NJT * NKT)       // 64

typedef __attribute__((ext_vector_type(8))) short short8v;
typedef __attribute__((ext_vector_type(4))) float f32x4;
typedef __attribute__((ext_vector_type(4))) int int4v;
typedef __attribute__((ext_vector_type(4))) uint uint4v;

#define WAITV0 asm volatile("s_waitcnt vmcnt(0)" ::: "memory")
#define BAR __builtin_amdgcn_s_barrier()

__device__ __forceinline__ void gld16(const ushort* g, ushort* l) {
  __builtin_amdgcn_global_load_lds(
      (const __attribute__((address_space(1))) uint32_t*)g,
      (__attribute__((address_space(3))) uint32_t*)l, 16, 0, 0);
}

// branchless sorted-insert into ascending 4-list (7 min/max)
#define INS4(L, xv)                                                  \
  do {                                                               \
    uint _x = (xv);                                                  \
    uint _l0 = _x < L[0] ? _x : L[0];                                \
    uint _h0 = _x < L[0] ? L[0] : _x;                                \
    L[0] = _l0;                                                      \
    uint _l1 = _h0 < L[1] ? _h0 : L[1];                              \
    uint _h1 = _h0 < L[1] ? L[1] : _h0;                              \
    L[1] = _l1;                                                      \
    uint _l2 = _h1 < L[2] ? _h1 : L[2];                              \
    uint _h2 = _h1 < L[2] ? L[2] : _h1;                              \
    L[2] = _l2;                                                      \
    L[3] = _h2 < L[3] ? _h2 : L[3];                                  \
  } while (0)

// branchless sorted-insert into ascending 8-list (15 min/max)
#define INS8(L, xv)                                                  \
  do {                                                               \
    uint _x = (xv);                                                  \
    uint _a0 = _x < L[0] ? _x : L[0];                                \
    uint _b0 = _x < L[0] ? L[0] : _x;                                \
    L[0] = _a0;                                                      \
    uint _a1 = _b0 < L[1] ? _b0 : L[1];                              \
    uint _b1 = _b0 < L[1] ? L[1] : _b0;                              \
    L[1] = _a1;                                                      \
    uint _a2 = _b1 < L[2] ? _b1 : L[2];                              \
    uint _b2 = _b1 < L[2] ? L[2] : _b1;                              \
    L[2] = _a2;                                                      \
    uint _a3 = _b2 < L[3] ? _b2 : L[3];                              \
    uint _b3 = _b2 < L[3] ? L[3] : _b2;                              \
    L[3] = _a3;                                                      \
    uint _a4 = _b3 < L[4] ? _b3 : L[4];                              \
    uint _b4 = _b3 < L[4] ? L[4] : _b3;                              \
    L[4] = _a4;                                                      \
    uint _a5 = _b4 < L[5] ? _b4 : L[5];                              \
    uint _b5 = _b4 < L[5] ? L[5] : _b4;                              \
    L[5] = _a5;                                                      \
    uint _a6 = _b5 < L[6] ? _b5 : L[6];                              \
    uint _b6 = _b5 < L[6] ? L[6] : _b5;                              \
    L[6] = _a6;                                                      \
    L[7] = _b6 < L[7] ? _b6 : L[7];                                  \
  } while (0)

// ---------------- kernel 0: sqb = |x|^2 + bias, bf16 copy ----------------
__global__ __launch_bounds__(64) void prep_kernel(const float* __restrict__ X,
                                                  float* __restrict__ sqb,
                                                  ushort* __restrict__ Xb) {
  const int i = blockIdx.x;
  const int lane = threadIdx.x;
  const float4 v0 = *(const float4*)&X[(size_t)i * D + lane * 8];
  const float4 v1 = *(const float4*)&X[(size_t)i * D + lane * 8 + 4];
  float vv[8] = {v0.x, v0.y, v0.z, v0.w, v1.x, v1.y, v1.z, v1.w};
  ushort h[8];
  float s = 0.f;
#pragma unroll
  for (int j = 0; j < 8; ++j) {
    s = fmaf(vv[j], vv[j], s);
    __hip_bfloat16 b = __float2bfloat16(vv[j]);
    h[j] = *(ushort*)&b;
  }
  *(int4v*)&Xb[(size_t)i * D + lane * 8] = *(int4v*)h;
#pragma unroll
  for (int off = 32; off; off >>= 1) s += __shfl_xor(s, off);
  if (lane == 0) sqb[i] = s + KEYBIAS;
}

// ---------------- kernel 1: swapped-operand MFMA GEMM, pure-register selection ----------------
// (unchanged from round 9)
__global__ __launch_bounds__(256, 4) void knn_kernel(const ushort* __restrict__ Xb,
                                                     const float* __restrict__ sqb,
                                                     uint* __restrict__ cand) {
  __shared__ ushort As[2][BI][BK];  // 16 KB
  __shared__ ushort Bs[2][BJ][BK];  // 16 KB

  const int i0 = blockIdx.x * BI;
  const int chunk = blockIdx.y;
  const int jbase = chunk * JCHUNK;
  const int tid = threadIdx.x;
  const int lane = tid & 63;
  const int wave = tid >> 6;
  const int wr = wave >> 1, wc = wave & 1;
  const int q = lane >> 4, cr = lane & 15;

  const int srow = tid >> 2, sg = tid & 3;
  const int scsw = (sg ^ ((srow >> 1) & 3)) * 8;
  const size_t aoff0 = (size_t)(i0 + srow) * D + scsw;
  const size_t aoff1 = (size_t)(i0 + 64 + srow) * D + scsw;
  const size_t boff0 = (size_t)(jbase + srow) * D + scsw;

  const int fcol = (q ^ ((cr >> 1) & 3)) * 8;

  uint Lst[4][4];
#pragma unroll
  for (int m = 0; m < 4; ++m)
#pragma unroll
    for (int k = 0; k < 4; ++k) Lst[m][k] = 0xFFFFFFFFu;

  auto STAGE = [&](int tt) {
    const int jt_ = tt >> 4;
    const int bf = tt & 1;
    const int ko = (tt & 15) * BK;
    gld16(Xb + aoff0 + ko, &As[bf][srow][sg * 8]);
    gld16(Xb + aoff1 + ko, &As[bf][64 + srow][sg * 8]);
    const size_t bo = boff0 + (size_t)jt_ * (BJ * D) + ko;
    gld16(Xb + bo, &Bs[bf][srow][sg * 8]);
    gld16(Xb + bo + (size_t)64 * D, &Bs[bf][64 + srow][sg * 8]);
  };

  f32x4 acc[4][4];  // [n][m]: n = j-group, m = i-group
#pragma unroll
  for (int n = 0; n < 4; ++n)
#pragma unroll
    for (int m = 0; m < 4; ++m) acc[n][m] = (f32x4){0.f, 0.f, 0.f, 0.f};

  STAGE(0);

#pragma unroll 1
  for (int t = 0; t < NT; ++t) {
    const int buf = t & 1;
    WAITV0;
    BAR;
    STAGE((t + 1) & (NT - 1));

    const ushort(*Ab)[BK] = As[buf];
    const ushort(*Bb)[BK] = Bs[buf];
    short8v a[4], b[4];
#pragma unroll
    for (int m = 0; m < 4; ++m)
      a[m] = *(const short8v*)&Ab[wr * 64 + m * 16 + cr][fcol];
#pragma unroll
    for (int n = 0; n < 4; ++n)
      b[n] = *(const short8v*)&Bb[wc * 64 + n * 16 + cr][fcol];
    __builtin_amdgcn_s_setprio(1);
#pragma unroll
    for (int n = 0; n < 4; ++n)
#pragma unroll
      for (int m = 0; m < 4; ++m)
        acc[n][m] = __builtin_amdgcn_mfma_f32_16x16x32_bf16(b[n], a[m], acc[n][m], 0, 0, 0);
    __builtin_amdgcn_s_setprio(0);

    if ((t & 15) == 15) {  // end of jt: register-only selection
      const int jt = t >> 4;
      const int jloc = jt * BJ + wc * 64 + q * 4;  // + n*16 + s
#pragma unroll
      for (int n = 0; n < 4; ++n) {
        const float4 s4 = *(const float4*)&sqb[jbase + jloc + n * 16];
        const uint ib = (uint)(jloc + n * 16);
#pragma unroll
        for (int m = 0; m < 4; ++m) {
          const float f0 = fmaf(-2.f, acc[n][m][0], s4.x);
          const float f1 = fmaf(-2.f, acc[n][m][1], s4.y);
          const float f2 = fmaf(-2.f, acc[n][m][2], s4.z);
          const float f3 = fmaf(-2.f, acc[n][m][3], s4.w);
          INS4(Lst[m], (__float_as_uint(f0) & 0xFFFFFC00u) | ib);
          INS4(Lst[m], (__float_as_uint(f1) & 0xFFFFFC00u) | (ib + 1));
          INS4(Lst[m], (__float_as_uint(f2) & 0xFFFFFC00u) | (ib + 2));
          INS4(Lst[m], (__float_as_uint(f3) & 0xFFFFFC00u) | (ib + 3));
        }
      }
#pragma unroll
      for (int n = 0; n < 4; ++n)
#pragma unroll
        for (int m = 0; m < 4; ++m) acc[n][m] = (f32x4){0.f, 0.f, 0.f, 0.f};
    }
  }

  // merge q-lanes (xor16 then xor32) -> top-8 of the wave's 256-stream per row
#pragma unroll
  for (int m = 0; m < 4; ++m) {
    uint L8[8];
#pragma unroll
    for (int k = 0; k < 4; ++k) {
      L8[k] = Lst[m][k];
      L8[4 + k] = 0xFFFFFFFFu;
    }
#pragma unroll
    for (int k = 0; k < 4; ++k) {
      const uint x = __shfl_xor(Lst[m][k], 16);
      INS8(L8, x);
    }
    uint tf[8];
#pragma unroll
    for (int k = 0; k < 8; ++k) tf[k] = __shfl_xor(L8[k], 32);
#pragma unroll
    for (int k = 0; k < 8; ++k) INS8(L8, tf[k]);
    if (q == 0) {
      const int gi = i0 + wr * 64 + m * 16 + cr;
      uint* dst = &cand[((size_t)gi * NCHUNK + chunk) * KSEL + wc * 8];
      *(uint4v*)dst = (uint4v){L8[0], L8[1], L8[2], L8[3]};
      *(uint4v*)(dst + 4) = (uint4v){L8[4], L8[5], L8[6], L8[7]};
    }
  }
}

// ---------------- kernel 2: direct top-10 merge (approx keys), Gram, solve, loss ----------------
// Neighbor SET is all that matters (Gram/solve/recon are permutation-invariant);
// approx-key membership flips at the 10/11 boundary are ~1e-3 in loss (margin 2.2e-2).
__global__ __launch_bounds__(256) void lle_loss_kernel(
    const float* __restrict__ X, const float* __restrict__ Z,
    const uint* __restrict__ cand, float* __restrict__ rowsse) {
  const int lane = threadIdx.x & 63;
  const int i = blockIdx.x * 4 + (threadIdx.x >> 6);

  // 256 entries (16 chunks x 16) -> unique u64 (approx key || gidx13)
  const uint4v pk4 = *(const uint4v*)&cand[(size_t)i * 256 + lane * 4];
  const int chk = lane >> 2;  // (lane*4+kk)>>4 for kk=0..3
  unsigned long long cvm[4];
#pragma unroll
  for (int kk = 0; kk < 4; ++kk) {
    const int g = chk * JCHUNK + (int)(pk4[kk] & 0x3FFu);
    const unsigned long long kv =
        ((unsigned long long)(pk4[kk] >> 10) << 13) | (unsigned long long)g;
    cvm[kk] = (g == i) ? ~0ull : kv;  // self-exclusion
  }

  // top-10 via 10x butterfly argmin; every lane keeps all results
  int nbrj[KNN];
#pragma unroll
  for (int k = 0; k < KNN; ++k) {
    const unsigned long long m01 = cvm[0] < cvm[1] ? cvm[0] : cvm[1];
    const unsigned long long m23 = cvm[2] < cvm[3] ? cvm[2] : cvm[3];
    unsigned long long mn = m01 < m23 ? m01 : m23;
#pragma unroll
    for (int off = 32; off; off >>= 1) {
      const unsigned long long o = __shfl_xor(mn, off);
      mn = o < mn ? o : mn;
    }
    nbrj[k] = (int)(mn & 0x1FFFull);
#pragma unroll
    for (int kk = 0; kk < 4; ++kk)
      cvm[kk] = (cvm[kk] == mn) ? ~0ull : cvm[kk];  // values unique
  }

  float xi[8];
  {
    const float4 v0 = *(const float4*)&X[(size_t)i * D + lane * 8];
    const float4 v1 = *(const float4*)&X[(size_t)i * D + lane * 8 + 4];
    xi[0] = v0.x; xi[1] = v0.y; xi[2] = v0.z; xi[3] = v0.w;
    xi[4] = v1.x; xi[5] = v1.y; xi[6] = v1.z; xi[7] = v1.w;
  }

  // diffs in registers (lane owns 8 contiguous dims)
  float df[KNN][8];
#pragma unroll
  for (int k = 0; k < KNN; ++k) {
    const int j = nbrj[k];
    const float4 u0 = *(const float4*)&X[(size_t)j * D + lane * 8];
    const float4 u1 = *(const float4*)&X[(size_t)j * D + lane * 8 + 4];
    df[k][0] = u0.x - xi[0]; df[k][1] = u0.y - xi[1];
    df[k][2] = u0.z - xi[2]; df[k][3] = u0.w - xi[3];
    df[k][4] = u1.x - xi[4]; df[k][5] = u1.y - xi[5];
    df[k][6] = u1.z - xi[6]; df[k][7] = u1.w - xi[7];
  }

  // Gram lower triangle via butterfly reductions -> every lane has C
  float C[KNN][KNN];
#pragma unroll
  for (int k = 0; k < KNN; ++k) {
#pragma unroll
    for (int l = 0; l <= k; ++l) {
      float p = 0.f;
#pragma unroll
      for (int c = 0; c < 8; ++c) p = fmaf(df[k][c], df[l][c], p);
#pragma unroll
      for (int off = 32; off; off >>= 1) p += __shfl_xor(p, off);
      C[k][l] = p;
    }
  }

  // all-lane static-register Cholesky + solve (zero LDS, zero divergence)
  float dinv[KNN];
#pragma unroll
  for (int j = 0; j < KNN; ++j) {
    float s = C[j][j] + REGC;
#pragma unroll
    for (int t = 0; t < KNN; ++t)
      if (t < j) s -= C[j][t] * C[j][t];
    const float dj = sqrtf(s);
    const float inv = 1.f / dj;
    dinv[j] = inv;
#pragma unroll
    for (int r2 = 0; r2 < KNN; ++r2) {
      if (r2 > j) {
        float s2 = C[r2][j];
#pragma unroll
        for (int t = 0; t < KNN; ++t)
          if (t < j) s2 -= C[r2][t] * C[j][t];
        C[r2][j] = s2 * inv;
      }
    }
  }
  float y[KNN], w[KNN];
#pragma unroll
  for (int r2 = 0; r2 < KNN; ++r2) {  // L y = 1
    float s = 1.f;
#pragma unroll
    for (int t = 0; t < KNN; ++t)
      if (t < r2) s -= C[r2][t] * y[t];
    y[r2] = s * dinv[r2];
  }
#pragma unroll
  for (int r2 = KNN - 1; r2 >= 0; --r2) {  // L^T w = y
    float s2 = y[r2];
#pragma unroll
    for (int t = 0; t < KNN; ++t)
      if (t > r2) s2 -= C[t][r2] * w[t];
    w[r2] = s2 * dinv[r2];
  }
  float ws = 0.f;
#pragma unroll
  for (int k = 0; k < KNN; ++k) ws += w[k];
  const float winv = 1.f / ws;

  // reconstruction (lane == output dim, DZ == 64)
  float zr = 0.f;
#pragma unroll
  for (int k = 0; k < KNN; ++k)
    zr = fmaf(w[k] * winv, Z[(size_t)nbrj[k] * DZ + lane], zr);
  const float e = zr - Z[(size_t)i * DZ + lane];
  float se = e * e;
#pragma unroll
  for (int off = 32; off; off >>= 1) se += __shfl_xor(se, off);
  if (lane == 0) rowsse[i] = se;  // plain store: no atomic contention
}

// ---------------- kernel 3: single-block final reduction ----------------
__global__ __launch_bounds__(256) void reduce_kernel(const float* __restrict__ rowsse,
                                                     float* __restrict__ out) {
  const int tid = threadIdx.x;
  float s = 0.f;
#pragma unroll
  for (int c = 0; c < N / 256; ++c) s += rowsse[c * 256 + tid];
#pragma unroll
  for (int off = 32; off; off >>= 1) s += __shfl_xor(s, off);
  __shared__ float part[4];
  if ((tid & 63) == 0) part[tid >> 6] = s;
  __syncthreads();
  if (tid == 0)
    out[0] = (part[0] + part[1] + part[2] + part[3]) * (1.f / ((float)N * DZ));
}

// ---------------- launch ----------------
extern "C" void kernel_launch(void* const* d_in, const int* in_sizes, int n_in,
                              void* d_out, int out_size, void* d_ws, size_t ws_size,
                              hipStream_t stream) {
  const float* X = (const float*)d_in[0];
  const float* Z = (const float*)d_in[1];
  float* out = (float*)d_out;

  char* ws = (char*)d_ws;
  float* sqb = (float*)ws;                                   // 32 KB
  float* rowsse = (float*)(ws + 32 * 1024);                  // 32 KB
  ushort* Xb = (ushort*)(ws + 64 * 1024);                    // 8 MB
  uint* cand = (uint*)(ws + 64 * 1024 + (size_t)N * D * 2);  // 8 MB

  prep_kernel<<<N, 64, 0, stream>>>(X, sqb, Xb);
  knn_kernel<<<dim3(N / BI, NCHUNK), 256, 0, stream>>>(Xb, sqb, cand);
  lle_loss_kernel<<<N / 4, 256, 0, stream>>>(X, Z, cand, rowsse);
  reduce_kernel<<<1, 256, 0, stream>>>(rowsse, out);
}

// Round 11
// 143.480 us; speedup vs baseline: 1.2048x; 1.0051x over previous
//
#include <hip/hip_runtime.h>
#include <hip/hip_bf16.h>
#include <float.h>
#include <stdint.h>

#define N 8192
#define D 512
#define DZ 64
#define KNN 10
#define KSEL 16
#define REGC 1e-6f
#define KEYBIAS 4096.0f

#define BI 128
#define BJ 128
#define BK 32
#define NCHUNK 16
#define JCHUNK (N / NCHUNK)  // 512
#define NJT (JCHUNK / BJ)    // 4

typedef __attribute__((ext_vector_type(8))) short short8v;
typedef __attribute__((ext_vector_type(4))) float f32x4;
typedef __attribute__((ext_vector_type(4))) int int4v;
typedef __attribute__((ext_vector_type(4))) uint uint4v;

#define WAITV0 asm volatile("s_waitcnt vmcnt(0)" ::: "memory")
#define BAR __builtin_amdgcn_s_barrier()

template <int OFFB>  // byte offset immediate on the global address
__device__ __forceinline__ void gldo(const ushort* g, ushort* l) {
  __builtin_amdgcn_global_load_lds(
      (const __attribute__((address_space(1))) uint32_t*)g,
      (__attribute__((address_space(3))) uint32_t*)l, 16, OFFB, 0);
}

// branchless sorted-insert into ascending 4-list (7 min/max)
#define INS4(L, xv)                                                  \
  do {                                                               \
    uint _x = (xv);                                                  \
    uint _l0 = _x < L[0] ? _x : L[0];                                \
    uint _h0 = _x < L[0] ? L[0] : _x;                                \
    L[0] = _l0;                                                      \
    uint _l1 = _h0 < L[1] ? _h0 : L[1];                              \
    uint _h1 = _h0 < L[1] ? L[1] : _h0;                              \
    L[1] = _l1;                                                      \
    uint _l2 = _h1 < L[2] ? _h1 : L[2];                              \
    uint _h2 = _h1 < L[2] ? L[2] : _h1;                              \
    L[2] = _l2;                                                      \
    L[3] = _h2 < L[3] ? _h2 : L[3];                                  \
  } while (0)

// branchless sorted-insert into ascending 8-list (15 min/max)
#define INS8(L, xv)                                                  \
  do {                                                               \
    uint _x = (xv);                                                  \
    uint _a0 = _x < L[0] ? _x : L[0];                                \
    uint _b0 = _x < L[0] ? L[0] : _x;                                \
    L[0] = _a0;                                                      \
    uint _a1 = _b0 < L[1] ? _b0 : L[1];                              \
    uint _b1 = _b0 < L[1] ? L[1] : _b0;                              \
    L[1] = _a1;                                                      \
    uint _a2 = _b1 < L[2] ? _b1 : L[2];                              \
    uint _b2 = _b1 < L[2] ? L[2] : _b1;                              \
    L[2] = _a2;                                                      \
    uint _a3 = _b2 < L[3] ? _b2 : L[3];                              \
    uint _b3 = _b2 < L[3] ? L[3] : _b2;                              \
    L[3] = _a3;                                                      \
    uint _a4 = _b3 < L[4] ? _b3 : L[4];                              \
    uint _b4 = _b3 < L[4] ? L[4] : _b3;                              \
    L[4] = _a4;                                                      \
    uint _a5 = _b4 < L[5] ? _b4 : L[5];                              \
    uint _b5 = _b4 < L[5] ? L[5] : _b4;                              \
    L[5] = _a5;                                                      \
    uint _a6 = _b5 < L[6] ? _b5 : L[6];                              \
    uint _b6 = _b5 < L[6] ? L[6] : _b5;                              \
    L[6] = _a6;                                                      \
    L[7] = _b6 < L[7] ? _b6 : L[7];                                  \
  } while (0)

// ---------------- kernel 0: sqb = |x|^2 + bias, bf16 copy ----------------
__global__ __launch_bounds__(64) void prep_kernel(const float* __restrict__ X,
                                                  float* __restrict__ sqb,
                                                  ushort* __restrict__ Xb) {
  const int i = blockIdx.x;
  const int lane = threadIdx.x;
  const float4 v0 = *(const float4*)&X[(size_t)i * D + lane * 8];
  const float4 v1 = *(const float4*)&X[(size_t)i * D + lane * 8 + 4];
  float vv[8] = {v0.x, v0.y, v0.z, v0.w, v1.x, v1.y, v1.z, v1.w};
  ushort h[8];
  float s = 0.f;
#pragma unroll
  for (int j = 0; j < 8; ++j) {
    s = fmaf(vv[j], vv[j], s);
    __hip_bfloat16 b = __float2bfloat16(vv[j]);
    h[j] = *(ushort*)&b;
  }
  *(int4v*)&Xb[(size_t)i * D + lane * 8] = *(int4v*)h;
#pragma unroll
  for (int off = 32; off; off >>= 1) s += __shfl_xor(s, off);
  if (lane == 0) sqb[i] = s + KEYBIAS;
}

// ---------------- kernel 1: swapped-operand MFMA GEMM, immediate-offset pipeline ----------------
// Same sync skeleton as round 10 (WAITV0; BAR; STAGE(next); compute), but the 16
// K-steps per jt are unrolled so every global_load_lds and ds_read uses a
// compile-time offset off a hoisted base pointer -- per-step address VALU ~0.
__global__ __launch_bounds__(256, 4) void knn_kernel(const ushort* __restrict__ Xb,
                                                     const float* __restrict__ sqb,
                                                     uint* __restrict__ cand) {
  __shared__ ushort As[2][BI][BK];  // 16 KB
  __shared__ ushort Bs[2][BJ][BK];  // 16 KB

  const int i0 = blockIdx.x * BI;
  const int chunk = blockIdx.y;
  const int jbase = chunk * JCHUNK;
  const int tid = threadIdx.x;
  const int lane = tid & 63;
  const int wave = tid >> 6;
  const int wr = wave >> 1, wc = wave & 1;
  const int q = lane >> 4, cr = lane & 15;

  // staging bases: thread -> 16B; LDS dest linear, source col pre-swizzled
  const int srow = tid >> 2, sg = tid & 3;
  const int scsw = (sg ^ ((srow >> 1) & 3)) * 8;
  const ushort* ap0 = Xb + (size_t)(i0 + srow) * D + scsw;        // kernel-constant
  const ushort* ap1 = ap0 + (size_t)64 * D;
  const ushort* bp0 = Xb + (size_t)(jbase + srow) * D + scsw;     // advances per jt
  const ushort* bp1 = bp0 + (size_t)64 * D;

  ushort* const a0d = &As[0][srow][sg * 8];   // LDS dests (buf offsets explicit)
  ushort* const a1d = &As[1][srow][sg * 8];
  ushort* const b0d = &Bs[0][srow][sg * 8];
  ushort* const b1d = &Bs[1][srow][sg * 8];

  // fragment read bases (swizzle reduces to lane constant); m/buf are immediates
  const int fcol = (q ^ ((cr >> 1) & 3)) * 8;
  const ushort* afr = &As[0][wr * 64 + cr][fcol];
  const ushort* bfr = &Bs[0][wc * 64 + cr][fcol];

  uint Lst[4][4];
#pragma unroll
  for (int m = 0; m < 4; ++m)
#pragma unroll
    for (int k = 0; k < 4; ++k) Lst[m][k] = 0xFFFFFFFFu;

  f32x4 acc[4][4];  // [n][m]: n = j-group, m = i-group
#pragma unroll
  for (int n = 0; n < 4; ++n)
#pragma unroll
    for (int m = 0; m < 4; ++m) acc[n][m] = (f32x4){0.f, 0.f, 0.f, 0.f};

// stage K-step KT (imm offset KT*64 B) into buffer (KT&1); PB0/PB1 select B base
#define STG(KT, PB0, PB1, AD, BD)          \
  gldo<(KT) * 64>(ap0, AD);                \
  gldo<(KT) * 64>(ap1, AD + 64 * BK);      \
  gldo<(KT) * 64>(PB0, BD);                \
  gldo<(KT) * 64>(PB1, BD + 64 * BK);

// compute K-step from buffer BUF (all LDS offsets immediate)
#define CMP(BUF)                                                              \
  do {                                                                        \
    short8v a_[4], b_[4];                                                     \
    a_[0] = *(const short8v*)(afr + (BUF) * 8192 + 0 * 512);                  \
    a_[1] = *(const short8v*)(afr + (BUF) * 8192 + 1 * 512);                  \
    a_[2] = *(const short8v*)(afr + (BUF) * 8192 + 2 * 512);                  \
    a_[3] = *(const short8v*)(afr + (BUF) * 8192 + 3 * 512);                  \
    b_[0] = *(const short8v*)(bfr + (BUF) * 8192 + 0 * 512);                  \
    b_[1] = *(const short8v*)(bfr + (BUF) * 8192 + 1 * 512);                  \
    b_[2] = *(const short8v*)(bfr + (BUF) * 8192 + 2 * 512);                  \
    b_[3] = *(const short8v*)(bfr + (BUF) * 8192 + 3 * 512);                  \
    __builtin_amdgcn_s_setprio(1);                                            \
    _Pragma("unroll") for (int n_ = 0; n_ < 4; ++n_)                          \
        _Pragma("unroll") for (int m_ = 0; m_ < 4; ++m_)                      \
            acc[n_][m_] = __builtin_amdgcn_mfma_f32_16x16x32_bf16(            \
                b_[n_], a_[m_], acc[n_][m_], 0, 0, 0);                        \
    __builtin_amdgcn_s_setprio(0);                                            \
  } while (0)

#define KSTEP(KT, PB0, PB1)                                                   \
  WAITV0;                                                                     \
  BAR;                                                                        \
  STG((KT) + 1, PB0, PB1, (((KT) + 1) & 1) ? a1d : a0d,                       \
      (((KT) + 1) & 1) ? b1d : b0d);                                          \
  CMP((KT) & 1);

  // prologue: stage jt0/kt0 into buf0
  STG(0, bp0, bp1, a0d, b0d);

#pragma unroll 1
  for (int jt = 0; jt < NJT; ++jt) {
    const ushort* bn0 = bp0 + (size_t)BJ * D;  // next jt's B base (jt=3: dummy)
    const ushort* bn1 = bn0 + (size_t)64 * D;

    KSTEP(0, bp0, bp1)
    KSTEP(1, bp0, bp1)
    KSTEP(2, bp0, bp1)
    KSTEP(3, bp0, bp1)
    KSTEP(4, bp0, bp1)
    KSTEP(5, bp0, bp1)
    KSTEP(6, bp0, bp1)
    KSTEP(7, bp0, bp1)
    KSTEP(8, bp0, bp1)
    KSTEP(9, bp0, bp1)
    KSTEP(10, bp0, bp1)
    KSTEP(11, bp0, bp1)
    KSTEP(12, bp0, bp1)
    KSTEP(13, bp0, bp1)
    KSTEP(14, bp0, bp1)
    // kt=15: stage NEXT jt's kt0 into buf0, compute from buf1
    WAITV0;
    BAR;
    gldo<0>(bn0, b0d);
    gldo<0>(bn1, b0d + 64 * BK);
    gldo<0>(ap0, a0d);
    gldo<0>(ap1, a0d + 64 * BK);
    CMP(1);

    // register-only selection (unchanged from round 10)
    const int jloc = jt * BJ + wc * 64 + q * 4;  // + n*16 + s
#pragma unroll
    for (int n = 0; n < 4; ++n) {
      const float4 s4 = *(const float4*)&sqb[jbase + jloc + n * 16];
      const uint ib = (uint)(jloc + n * 16);
#pragma unroll
      for (int m = 0; m < 4; ++m) {
        const float f0 = fmaf(-2.f, acc[n][m][0], s4.x);
        const float f1 = fmaf(-2.f, acc[n][m][1], s4.y);
        const float f2 = fmaf(-2.f, acc[n][m][2], s4.z);
        const float f3 = fmaf(-2.f, acc[n][m][3], s4.w);
        INS4(Lst[m], (__float_as_uint(f0) & 0xFFFFFC00u) | ib);
        INS4(Lst[m], (__float_as_uint(f1) & 0xFFFFFC00u) | (ib + 1));
        INS4(Lst[m], (__float_as_uint(f2) & 0xFFFFFC00u) | (ib + 2));
        INS4(Lst[m], (__float_as_uint(f3) & 0xFFFFFC00u) | (ib + 3));
      }
    }
#pragma unroll
    for (int n = 0; n < 4; ++n)
#pragma unroll
      for (int m = 0; m < 4; ++m) acc[n][m] = (f32x4){0.f, 0.f, 0.f, 0.f};

    bp0 = bn0;
    bp1 = bn1;
  }

  // merge q-lanes (xor16 then xor32) -> top-8 of the wave's 256-stream per row
#pragma unroll
  for (int m = 0; m < 4; ++m) {
    uint L8[8];
#pragma unroll
    for (int k = 0; k < 4; ++k) {
      L8[k] = Lst[m][k];
      L8[4 + k] = 0xFFFFFFFFu;
    }
#pragma unroll
    for (int k = 0; k < 4; ++k) {
      const uint x = __shfl_xor(Lst[m][k], 16);
      INS8(L8, x);
    }
    uint tf[8];
#pragma unroll
    for (int k = 0; k < 8; ++k) tf[k] = __shfl_xor(L8[k], 32);
#pragma unroll
    for (int k = 0; k < 8; ++k) INS8(L8, tf[k]);
    if (q == 0) {
      const int gi = i0 + wr * 64 + m * 16 + cr;
      uint* dst = &cand[((size_t)gi * NCHUNK + chunk) * KSEL + wc * 8];
      *(uint4v*)dst = (uint4v){L8[0], L8[1], L8[2], L8[3]};
      *(uint4v*)(dst + 4) = (uint4v){L8[4], L8[5], L8[6], L8[7]};
    }
  }
}

// ---------------- kernel 2: direct top-10 merge, Gram, solve, loss (unchanged) ----------------
__global__ __launch_bounds__(256) void lle_loss_kernel(
    const float* __restrict__ X, const float* __restrict__ Z,
    const uint* __restrict__ cand, float* __restrict__ rowsse) {
  const int lane = threadIdx.x & 63;
  const int i = blockIdx.x * 4 + (threadIdx.x >> 6);

  const uint4v pk4 = *(const uint4v*)&cand[(size_t)i * 256 + lane * 4];
  const int chk = lane >> 2;
  unsigned long long cvm[4];
#pragma unroll
  for (int kk = 0; kk < 4; ++kk) {
    const int g = chk * JCHUNK + (int)(pk4[kk] & 0x3FFu);
    const unsigned long long kv =
        ((unsigned long long)(pk4[kk] >> 10) << 13) | (unsigned long long)g;
    cvm[kk] = (g == i) ? ~0ull : kv;  // self-exclusion
  }

  int nbrj[KNN];
#pragma unroll
  for (int k = 0; k < KNN; ++k) {
    const unsigned long long m01 = cvm[0] < cvm[1] ? cvm[0] : cvm[1];
    const unsigned long long m23 = cvm[2] < cvm[3] ? cvm[2] : cvm[3];
    unsigned long long mn = m01 < m23 ? m01 : m23;
#pragma unroll
    for (int off = 32; off; off >>= 1) {
      const unsigned long long o = __shfl_xor(mn, off);
      mn = o < mn ? o : mn;
    }
    nbrj[k] = (int)(mn & 0x1FFFull);
#pragma unroll
    for (int kk = 0; kk < 4; ++kk)
      cvm[kk] = (cvm[kk] == mn) ? ~0ull : cvm[kk];
  }

  float xi[8];
  {
    const float4 v0 = *(const float4*)&X[(size_t)i * D + lane * 8];
    const float4 v1 = *(const float4*)&X[(size_t)i * D + lane * 8 + 4];
    xi[0] = v0.x; xi[1] = v0.y; xi[2] = v0.z; xi[3] = v0.w;
    xi[4] = v1.x; xi[5] = v1.y; xi[6] = v1.z; xi[7] = v1.w;
  }

  float df[KNN][8];
#pragma unroll
  for (int k = 0; k < KNN; ++k) {
    const int j = nbrj[k];
    const float4 u0 = *(const float4*)&X[(size_t)j * D + lane * 8];
    const float4 u1 = *(const float4*)&X[(size_t)j * D + lane * 8 + 4];
    df[k][0] = u0.x - xi[0]; df[k][1] = u0.y - xi[1];
    df[k][2] = u0.z - xi[2]; df[k][3] = u0.w - xi[3];
    df[k][4] = u1.x - xi[4]; df[k][5] = u1.y - xi[5];
    df[k][6] = u1.z - xi[6]; df[k][7] = u1.w - xi[7];
  }

  float C[KNN][KNN];
#pragma unroll
  for (int k = 0; k < KNN; ++k) {
#pragma unroll
    for (int l = 0; l <= k; ++l) {
      float p = 0.f;
#pragma unroll
      for (int c = 0; c < 8; ++c) p = fmaf(df[k][c], df[l][c], p);
#pragma unroll
      for (int off = 32; off; off >>= 1) p += __shfl_xor(p, off);
      C[k][l] = p;
    }
  }

  float dinv[KNN];
#pragma unroll
  for (int j = 0; j < KNN; ++j) {
    float s = C[j][j] + REGC;
#pragma unroll
    for (int t = 0; t < KNN; ++t)
      if (t < j) s -= C[j][t] * C[j][t];
    const float dj = sqrtf(s);
    const float inv = 1.f / dj;
    dinv[j] = inv;
#pragma unroll
    for (int r2 = 0; r2 < KNN; ++r2) {
      if (r2 > j) {
        float s2 = C[r2][j];
#pragma unroll
        for (int t = 0; t < KNN; ++t)
          if (t < j) s2 -= C[r2][t] * C[j][t];
        C[r2][j] = s2 * inv;
      }
    }
  }
  float y[KNN], w[KNN];
#pragma unroll
  for (int r2 = 0; r2 < KNN; ++r2) {
    float s = 1.f;
#pragma unroll
    for (int t = 0; t < KNN; ++t)
      if (t < r2) s -= C[r2][t] * y[t];
    y[r2] = s * dinv[r2];
  }
#pragma unroll
  for (int r2 = KNN - 1; r2 >= 0; --r2) {
    float s2 = y[r2];
#pragma unroll
    for (int t = 0; t < KNN; ++t)
      if (t > r2) s2 -= C[t][r2] * w[t];
    w[r2] = s2 * dinv[r2];
  }
  float ws = 0.f;
#pragma unroll
  for (int k = 0; k < KNN; ++k) ws += w[k];
  const float winv = 1.f / ws;

  float zr = 0.f;
#pragma unroll
  for (int k = 0; k < KNN; ++k)
    zr = fmaf(w[k] * winv, Z[(size_t)nbrj[k] * DZ + lane], zr);
  const float e = zr - Z[(size_t)i * DZ + lane];
  float se = e * e;
#pragma unroll
  for (int off = 32; off; off >>= 1) se += __shfl_xor(se, off);
  if (lane == 0) rowsse[i] = se;
}

// ---------------- kernel 3: single-block final reduction ----------------
__global__ __launch_bounds__(256) void reduce_kernel(const float* __restrict__ rowsse,
                                                     float* __restrict__ out) {
  const int tid = threadIdx.x;
  float s = 0.f;
#pragma unroll
  for (int c = 0; c < N / 256; ++c) s += rowsse[c * 256 + tid];
#pragma unroll
  for (int off = 32; off; off >>= 1) s += __shfl_xor(s, off);
  __shared__ float part[4];
  if ((tid & 63) == 0) part[tid >> 6] = s;
  __syncthreads();
  if (tid == 0)
    out[0] = (part[0] + part[1] + part[2] + part[3]) * (1.f / ((float)N * DZ));
}

// ---------------- launch ----------------
extern "C" void kernel_launch(void* const* d_in, const int* in_sizes, int n_in,
                              void* d_out, int out_size, void* d_ws, size_t ws_size,
                              hipStream_t stream) {
  const float* X = (const float*)d_in[0];
  const float* Z = (const float*)d_in[1];
  float* out = (float*)d_out;

  char* ws = (char*)d_ws;
  float* sqb = (float*)ws;                                   // 32 KB
  float* rowsse = (float*)(ws + 32 * 1024);                  // 32 KB
  ushort* Xb = (ushort*)(ws + 64 * 1024);                    // 8 MB
  uint* cand = (uint*)(ws + 64 * 1024 + (size_t)N * D * 2);  // 8 MB

  prep_kernel<<<N, 64, 0, stream>>>(X, sqb, Xb);
  knn_kernel<<<dim3(N / BI, NCHUNK), 256, 0, stream>>>(Xb, sqb, cand);
  lle_loss_kernel<<<N / 4, 256, 0, stream>>>(X, Z, cand, rowsse);
  reduce_kernel<<<1, 256, 0, stream>>>(rowsse, out);
}